// Round 4
// baseline (13256.564 us; speedup 1.0000x reference)
//
#include <hip/hip_runtime.h>
#include <math.h>

#define B_   8
#define S_   64
#define N_   100
#define D_   1024
#define ND_  768
#define BN_  800
#define G3_  3072
#define G6_  6144
#define NB_EPRE 32

typedef __bf16 bf16x8 __attribute__((ext_vector_type(8)));
typedef float f32x4 __attribute__((ext_vector_type(4)));

#define MFMA __builtin_amdgcn_mfma_f32_16x16x32_bf16

static __device__ __forceinline__ float wave_sum(float v) {
    for (int off = 32; off > 0; off >>= 1) v += __shfl_down(v, off, 64);
    return v;
}

// All 256 threads must call; returns full-block sum to every thread.
static __device__ __forceinline__ float block_sum(float v) {
    __shared__ float red_[8];
    float w = wave_sum(v);
    int lane = threadIdx.x & 63, wid = threadIdx.x >> 6;
    __syncthreads();               // protect red_ reuse across calls
    if (lane == 0) red_[wid] = w;
    __syncthreads();
    float t = 0.f;
    for (int i = 0; i < 4; ++i) t += red_[i];
    return t;
}

static __device__ __forceinline__ float gelu_f(float x) {
    return 0.5f * x * (1.f + erff(x * 0.70710678118654752f));
}

static __device__ __forceinline__ unsigned short f2bf(float x) {
    union { float f; unsigned u; } v; v.f = x;
    unsigned r = v.u + 0x7FFFu + ((v.u >> 16) & 1u);
    return (unsigned short)(r >> 16);
}

// split: x ~= hi + lo, each bf16; residual error ~2^-17 relative
static __device__ __forceinline__ void f2bfs(float x, unsigned short& hi, unsigned short& lo) {
    unsigned short h = f2bf(x);
    union { unsigned u; float f; } vh; vh.u = (unsigned)h << 16;
    hi = h; lo = f2bf(x - vh.f);
}

static __device__ __forceinline__ void f2bfs4(float4 v, ushort4& h, ushort4& l) {
    f2bfs(v.x, h.x, l.x); f2bfs(v.y, h.y, l.y);
    f2bfs(v.z, h.z, l.z); f2bfs(v.w, h.w, l.w);
}

// ---------------------------------------------------------------------------
// fp32 -> split-bf16 2D convert (strided dst for the W_cat concat). cols%4==0.
// ---------------------------------------------------------------------------
__global__ __launch_bounds__(256) void k_f2bfsplit(
    const float* __restrict__ src, unsigned short* __restrict__ dhi,
    unsigned short* __restrict__ dlo, int rows, int cols, int ldd)
{
    size_t n = (size_t)rows * cols;
    size_t i = ((size_t)blockIdx.x * 256 + threadIdx.x) * 4;
    if (i >= n) return;
    int r = (int)(i / cols);
    int c = (int)(i - (size_t)r * cols);
    float4 v = *(const float4*)(src + i);
    ushort4 h, l; f2bfs4(v, h, l);
    *(ushort4*)(dhi + (size_t)r * ldd + c) = h;
    *(ushort4*)(dlo + (size_t)r * ldd + c) = l;
}

// ---------------------------------------------------------------------------
// Split MFMA GEMM (sw-pipelined): C[M,Nc] = (Ah+Al)@(Wh+Wl)^T (+bias). fp32 out.
// 3-term: AhWh + AhWl + AlWh. TM=32, TN=128, K%64==0. Grid (Nc/128, ceil(M/32)).
// ---------------------------------------------------------------------------
__global__ __launch_bounds__(256) void k_mfma_nt(
    const unsigned short* __restrict__ Ah, const unsigned short* __restrict__ Al,
    const unsigned short* __restrict__ Wh, const unsigned short* __restrict__ Wl,
    const float* __restrict__ bias, float* __restrict__ C,
    int M, int Nc, int K)
{
    int m0 = blockIdx.y * 32; if (m0 >= M) return;
    int n0 = blockIdx.x * 128;
    __shared__ unsigned short sAh[32][72], sAl[32][72];
    __shared__ unsigned short sBh[128][72], sBl[128][72];
    int tid = threadIdx.x;
    int w = tid >> 6, l = tid & 63;
    int l15 = l & 15, q = l >> 4;
    int wn = w * 32;
    int arow = tid >> 3, achk = (tid & 7) * 8;
    int gm = m0 + arow;
    f32x4 acc[2][2] = {};
    uint4 pah = make_uint4(0u,0u,0u,0u), pal = pah;
    uint4 pbh[4], pbl[4];
    // prologue prefetch k0=0
    if (gm < M) {
        pah = *(const uint4*)(Ah + (size_t)gm * K + achk);
        pal = *(const uint4*)(Al + (size_t)gm * K + achk);
    }
    for (int i = 0; i < 4; ++i) {
        int r = arow + 32 * i;
        pbh[i] = *(const uint4*)(Wh + (size_t)(n0 + r) * K + achk);
        pbl[i] = *(const uint4*)(Wl + (size_t)(n0 + r) * K + achk);
    }
    for (int k0 = 0; k0 < K; k0 += 64) {
        *(uint4*)(&sAh[arow][achk]) = pah;
        *(uint4*)(&sAl[arow][achk]) = pal;
        for (int i = 0; i < 4; ++i) {
            *(uint4*)(&sBh[arow + 32*i][achk]) = pbh[i];
            *(uint4*)(&sBl[arow + 32*i][achk]) = pbl[i];
        }
        __syncthreads();
        int kn = k0 + 64;
        if (kn < K) {
            if (gm < M) {
                pah = *(const uint4*)(Ah + (size_t)gm * K + kn + achk);
                pal = *(const uint4*)(Al + (size_t)gm * K + kn + achk);
            }
            for (int i = 0; i < 4; ++i) {
                int r = arow + 32 * i;
                pbh[i] = *(const uint4*)(Wh + (size_t)(n0 + r) * K + kn + achk);
                pbl[i] = *(const uint4*)(Wl + (size_t)(n0 + r) * K + kn + achk);
            }
        }
#pragma unroll
        for (int ks = 0; ks < 64; ks += 32) {
            bf16x8 a0h = *(const bf16x8*)(&sAh[l15][ks + q*8]);
            bf16x8 a1h = *(const bf16x8*)(&sAh[16 + l15][ks + q*8]);
            bf16x8 a0l = *(const bf16x8*)(&sAl[l15][ks + q*8]);
            bf16x8 a1l = *(const bf16x8*)(&sAl[16 + l15][ks + q*8]);
            bf16x8 b0h = *(const bf16x8*)(&sBh[wn + l15][ks + q*8]);
            bf16x8 b1h = *(const bf16x8*)(&sBh[wn + 16 + l15][ks + q*8]);
            bf16x8 b0l = *(const bf16x8*)(&sBl[wn + l15][ks + q*8]);
            bf16x8 b1l = *(const bf16x8*)(&sBl[wn + 16 + l15][ks + q*8]);
            acc[0][0] = MFMA(a0h, b0h, acc[0][0], 0,0,0);
            acc[0][0] = MFMA(a0h, b0l, acc[0][0], 0,0,0);
            acc[0][0] = MFMA(a0l, b0h, acc[0][0], 0,0,0);
            acc[0][1] = MFMA(a0h, b1h, acc[0][1], 0,0,0);
            acc[0][1] = MFMA(a0h, b1l, acc[0][1], 0,0,0);
            acc[0][1] = MFMA(a0l, b1h, acc[0][1], 0,0,0);
            acc[1][0] = MFMA(a1h, b0h, acc[1][0], 0,0,0);
            acc[1][0] = MFMA(a1h, b0l, acc[1][0], 0,0,0);
            acc[1][0] = MFMA(a1l, b0h, acc[1][0], 0,0,0);
            acc[1][1] = MFMA(a1h, b1h, acc[1][1], 0,0,0);
            acc[1][1] = MFMA(a1h, b1l, acc[1][1], 0,0,0);
            acc[1][1] = MFMA(a1l, b1h, acc[1][1], 0,0,0);
        }
        __syncthreads();
    }
    for (int mi = 0; mi < 2; ++mi)
        for (int nj = 0; nj < 2; ++nj)
            for (int r = 0; r < 4; ++r) {
                int row = mi*16 + q*4 + r;
                int gmo = m0 + row;
                int cl = wn + nj*16 + l15;
                if (gmo < M) {
                    float bv = bias ? bias[n0 + cl] : 0.f;
                    C[(size_t)gmo * Nc + n0 + cl] = acc[mi][nj][r] + bv;
                }
            }
}

// ---------------------------------------------------------------------------
// h0 = mask * (type_embed[type] + LN(P, name_ln)); writes fp32 h + split mirror
// ---------------------------------------------------------------------------
__global__ __launch_bounds__(256) void k_h0(
    const float* __restrict__ P, const int* __restrict__ etype,
    const int* __restrict__ emask, const float* __restrict__ temb,
    const float* __restrict__ g, const float* __restrict__ bt,
    float* __restrict__ h, unsigned short* __restrict__ hh, unsigned short* __restrict__ hl)
{
    int bn = blockIdx.x, tid = threadIdx.x;
    int t = etype[bn], mk = emask[bn];
    float x[4]; float lsum = 0.f;
    for (int k = 0; k < 4; ++k) { x[k] = P[(size_t)bn*D_ + tid + 256*k]; lsum += x[k]; }
    float mean = block_sum(lsum) * (1.f / D_);
    float lv = 0.f;
    for (int k = 0; k < 4; ++k) { float d = x[k] - mean; lv += d * d; }
    float inv = rsqrtf(block_sum(lv) * (1.f / D_) + 1e-5f);
    for (int k = 0; k < 4; ++k) {
        int d = tid + 256*k;
        float y = (x[k] - mean) * inv * g[d] + bt[d];
        float hv = mk ? (temb[(size_t)t*D_ + d] + y) : 0.f;
        h[(size_t)bn*D_ + d] = hv;
        unsigned short sh, sl; f2bfs(hv, sh, sl);
        hh[(size_t)bn*D_ + d] = sh;
        hl[(size_t)bn*D_ + d] = sl;
    }
}

// ---------------------------------------------------------------------------
// Step A: roles, wsum, mean_ent. Grid (B_, 4): block handles 256 d's.
// ---------------------------------------------------------------------------
__global__ __launch_bounds__(256) void k_step_a(
    const float* __restrict__ inc, const int* __restrict__ emask,
    const float* __restrict__ h, float* __restrict__ roles,
    float* __restrict__ mean_ent, int* __restrict__ cnt, int s)
{
    int b = blockIdx.x, tid = threadIdx.x;
    __shared__ float sroles[N_];
    float r = 0.f;
    if (tid < N_) {
        float iv = inc[((size_t)b*N_ + tid)*S_ + s];
        r = emask[b*N_ + tid] ? iv : 0.f;
        sroles[tid] = r;
        if (blockIdx.y == 0) roles[b*N_ + tid] = r;
    }
    float tot = block_sum(r);           // also orders sroles stores
    if (tid == 0 && b == 0 && blockIdx.y == 0) *cnt = 0;
    float inv = 1.f / fmaxf(tot, 1.f);
    int d = blockIdx.y * 256 + tid;
    float acc = 0.f;
    for (int n = 0; n < N_; ++n) acc += sroles[n] * h[((size_t)b*N_ + n)*D_ + d];
    mean_ent[b*D_ + d] = acc * inv;
}

// ---------------------------------------------------------------------------
// Step B: blocks [0,32): e_pre = n2e(mean_ent)+t2e(x_s)+biases (pre-LN)
//         blocks [32,832): per-(b,n) arc/int contexts + active compaction
// ctx loops: j OUTER, d inner (float4) — independent coalesced loads.
// ---------------------------------------------------------------------------
__global__ __launch_bounds__(256) void k_step_b(
    const float* __restrict__ scene, const float* __restrict__ inc,
    const float* __restrict__ h, const float* __restrict__ esbuf,
    const float* __restrict__ n2eW, const float* __restrict__ n2eb,
    const float* __restrict__ t2eW, const float* __restrict__ t2eb,
    const float* __restrict__ roles, const float* __restrict__ mean_ent,
    float* __restrict__ e_pre, float* __restrict__ ctxa, float* __restrict__ ctxi,
    int* __restrict__ cnt, int* __restrict__ list, float* __restrict__ rowrole,
    int s)
{
    int tid = threadIdx.x;
    if (blockIdx.x < NB_EPRE) {
        __shared__ float sme[B_][D_ + 4];
        __shared__ float sxs[B_][D_ + 4];
        for (int i = tid; i < B_*D_; i += 256) {
            int b2 = i >> 10, j = i & (D_ - 1);
            sme[b2][j] = mean_ent[i];
            sxs[b2][j] = scene[((size_t)b2*S_ + s)*D_ + j];
        }
        __syncthreads();
        int il = tid >> 3, b = tid & 7;
        int i = blockIdx.x * 32 + il;
        float acc = n2eb[i] + t2eb[i];
        const float* wn = n2eW + (size_t)i * D_;
        const float* wt = t2eW + (size_t)i * D_;
        for (int j = 0; j < D_; j += 4) {
            float4 a = *(const float4*)(wn + j);
            float4 c = *(const float4*)(wt + j);
            acc += a.x*sme[b][j] + a.y*sme[b][j+1] + a.z*sme[b][j+2] + a.w*sme[b][j+3];
            acc += c.x*sxs[b][j] + c.y*sxs[b][j+1] + c.z*sxs[b][j+2] + c.w*sxs[b][j+3];
        }
        e_pre[b*D_ + i] = acc;
    } else {
        int m = blockIdx.x - NB_EPRE;
        int b = m / N_, n = m - b * N_;
        float r = roles[m];
        if (r <= 0.f) return;
        __shared__ int sidx, nwa, nwi;
        __shared__ float wav[S_]; __shared__ int wai[S_];
        __shared__ float wiv[N_]; __shared__ int wii[N_];
        if (tid == 0) { sidx = atomicAdd(cnt, 1); nwa = 0; nwi = 0; }
        __syncthreads();
        int idx = sidx;
        if (tid == 0) { list[idx] = m; rowrole[idx] = r; }
        float wa = 0.f;
        if (tid < s) {
            float denom = fmaxf((float)(s - 1), 1.f);
            float iv = inc[(size_t)m*S_ + tid];
            if (iv > 0.f) {
                wa = iv * r * expf(-1.f + (float)tid / denom);
                int p = atomicAdd(&nwa, 1);
                wav[p] = wa; wai[p] = tid;
            }
        }
        float denA = block_sum(wa);
        float wi = 0.f;
        if (tid < N_ && tid != n) {
            float rm = roles[b*N_ + tid];
            if (rm > 0.f) {
                wi = r * rm;
                int p = atomicAdd(&nwi, 1);
                wiv[p] = wi; wii[p] = tid;
            }
        }
        float denI = block_sum(wi);
        __syncthreads();
        float sclA = 1.f / fmaxf(denA, 1e-8f);
        float sclI = 1.f / fmaxf(denI, 1e-8f);
        int na = nwa, ni = nwi;
        // j-outer, d-inner: each thread owns 4 consecutive d's (float4)
        float4 aa = make_float4(0.f,0.f,0.f,0.f);
        for (int j = 0; j < na; ++j) {
            float wj = wav[j];
            float4 v = *((const float4*)(esbuf + ((size_t)b*S_ + wai[j])*D_) + tid);
            aa.x += wj*v.x; aa.y += wj*v.y; aa.z += wj*v.z; aa.w += wj*v.w;
        }
        aa.x *= sclA; aa.y *= sclA; aa.z *= sclA; aa.w *= sclA;
        *((float4*)(ctxa + (size_t)idx*D_) + tid) = aa;
        float4 ii = make_float4(0.f,0.f,0.f,0.f);
        for (int j = 0; j < ni; ++j) {
            float wj = wiv[j];
            float4 v = *((const float4*)(h + ((size_t)b*N_ + wii[j])*D_) + tid);
            ii.x += wj*v.x; ii.y += wj*v.y; ii.z += wj*v.z; ii.w += wj*v.w;
        }
        ii.x *= sclI; ii.y *= sclI; ii.z *= sclI; ii.w *= sclI;
        *((float4*)(ctxi + (size_t)idx*D_) + tid) = ii;
    }
}

// ---------------------------------------------------------------------------
// Step C: e_s = LN(e_pre) -> esbuf[b,s,:]; gate[b,0..2] via softmax(MLP(e_s))
// ---------------------------------------------------------------------------
__global__ __launch_bounds__(256) void k_step_c(
    const float* __restrict__ e_pre, const float* __restrict__ elng, const float* __restrict__ elnb,
    const float* __restrict__ gW1, const float* __restrict__ gb1,
    const float* __restrict__ gW2, const float* __restrict__ gb2,
    float* __restrict__ esbuf, float* __restrict__ gate, int s)
{
    int b = blockIdx.x, tid = threadIdx.x;
    __shared__ float se[D_];
    float x[4]; float lsum = 0.f;
    for (int k = 0; k < 4; ++k) { x[k] = e_pre[b*D_ + tid + 256*k]; lsum += x[k]; }
    float mean = block_sum(lsum) * (1.f / D_);
    float lv = 0.f;
    for (int k = 0; k < 4; ++k) { float d = x[k] - mean; lv += d * d; }
    float inv = rsqrtf(block_sum(lv) * (1.f / D_) + 1e-5f);
    for (int k = 0; k < 4; ++k) {
        int d = tid + 256*k;
        float y = (x[k] - mean) * inv * elng[d] + elnb[d];
        se[d] = y;
        esbuf[((size_t)b*S_ + s)*D_ + d] = y;
    }
    __syncthreads();
    float acc = gb1[tid];
    const float* w1 = gW1 + (size_t)tid * D_;
    for (int j = 0; j < D_; j += 4) {
        float4 w = *(const float4*)(w1 + j);
        acc += w.x*se[j] + w.y*se[j+1] + w.z*se[j+2] + w.w*se[j+3];
    }
    float hg = gelu_f(acc);
    __shared__ float sh[256];
    sh[tid] = hg;
    float g[3];
    for (int c = 0; c < 3; ++c)
        g[c] = block_sum(gW2[c*256 + tid] * sh[tid]) + gb2[c];
    float mx = fmaxf(g[0], fmaxf(g[1], g[2]));
    float e0 = expf(g[0]-mx), e1 = expf(g[1]-mx), e2 = expf(g[2]-mx);
    float si = 1.f / (e0 + e1 + e2);
    if (tid == 0) { gate[b*4+0] = e0*si; gate[b*4+1] = e1*si; gate[b*4+2] = e2*si; }
}

// ---------------------------------------------------------------------------
// msg MFMA GEMM (split, pipelined, on-the-fly A): A' = [g0*e_s|g1*ctxa|g2*ctxi]
// built + split during staging from fp32 sources. K=3072, TM=32, TN=64.
// Grid (16, 25). Writes split msg planes.
// ---------------------------------------------------------------------------
__global__ __launch_bounds__(256) void k_mfma_msg(
    const float* __restrict__ ctxa, const float* __restrict__ ctxi,
    const float* __restrict__ esbuf,
    const unsigned short* __restrict__ Wh, const unsigned short* __restrict__ Wl,
    const float* __restrict__ gate, const int* __restrict__ list,
    const int* __restrict__ cnt, const float* __restrict__ rowrole,
    const float* __restrict__ msB, const float* __restrict__ maB,
    const float* __restrict__ miB, const float* __restrict__ rolew,
    unsigned short* __restrict__ msgh, unsigned short* __restrict__ msgl, int s)
{
    int M = *cnt;
    int m0 = blockIdx.y * 32; if (m0 >= M) return;
    int n0 = blockIdx.x * 64;
    __shared__ unsigned short sAh[32][72], sAl[32][72];
    __shared__ unsigned short sBh[64][72], sBl[64][72];
    __shared__ float sg0[32], sg1[32], sg2[32], srr[32];
    __shared__ int sb[32];
    int tid = threadIdx.x;
    if (tid < 32) {
        int gm = m0 + tid;
        float g0 = 0.f, g1 = 0.f, g2 = 0.f, rv = 0.f; int b = 0;
        if (gm < M) {
            b = list[gm] / N_;
            g0 = gate[b*4]; g1 = (s > 0) ? gate[b*4+1] : 0.f; g2 = gate[b*4+2];
            rv = rowrole[gm];
        }
        sg0[tid] = g0; sg1[tid] = g1; sg2[tid] = g2; srr[tid] = rv; sb[tid] = b;
    }
    __syncthreads();
    int w = tid >> 6, l = tid & 63;
    int l15 = l & 15, q = l >> 4;
    int wm = (w & 1) * 16, wn = (w >> 1) * 32;
    int arow = tid >> 3, achk = (tid & 7) * 8;
    int gmA = m0 + arow;
    f32x4 acc[2] = {};
    float4 pa0 = make_float4(0.f,0.f,0.f,0.f), pa1 = pa0;
    uint4 pbh0, pbh1, pbl0, pbl1;
    // A-load helper (inline): k-chunk -> fp32 gated
    #define LOAD_A(kk) do { \
        pa0 = make_float4(0.f,0.f,0.f,0.f); pa1 = pa0; \
        if (gmA < M) { \
            int kg = (kk) + achk; int seg = kg >> 10; int ko = kg & (D_ - 1); \
            const float* base; float sc; \
            if (seg == 0)      { base = esbuf + ((size_t)sb[arow]*S_ + s)*D_ + ko; sc = sg0[arow]; } \
            else if (seg == 1) { base = ctxa + (size_t)gmA*D_ + ko; sc = sg1[arow]; } \
            else               { base = ctxi + (size_t)gmA*D_ + ko; sc = sg2[arow]; } \
            pa0 = *(const float4*)(base); pa1 = *(const float4*)(base + 4); \
            pa0.x *= sc; pa0.y *= sc; pa0.z *= sc; pa0.w *= sc; \
            pa1.x *= sc; pa1.y *= sc; pa1.z *= sc; pa1.w *= sc; \
        } } while (0)
    #define LOAD_B(kk) do { \
        pbh0 = *(const uint4*)(Wh + (size_t)(n0 + arow) * G3_ + (kk) + achk); \
        pbh1 = *(const uint4*)(Wh + (size_t)(n0 + arow + 32) * G3_ + (kk) + achk); \
        pbl0 = *(const uint4*)(Wl + (size_t)(n0 + arow) * G3_ + (kk) + achk); \
        pbl1 = *(const uint4*)(Wl + (size_t)(n0 + arow + 32) * G3_ + (kk) + achk); \
    } while (0)
    LOAD_A(0); LOAD_B(0);
    for (int k0 = 0; k0 < G3_; k0 += 64) {
        ushort4 h0, l0, h1, l1;
        f2bfs4(pa0, h0, l0); f2bfs4(pa1, h1, l1);
        *(ushort4*)(&sAh[arow][achk]) = h0; *(ushort4*)(&sAh[arow][achk+4]) = h1;
        *(ushort4*)(&sAl[arow][achk]) = l0; *(ushort4*)(&sAl[arow][achk+4]) = l1;
        *(uint4*)(&sBh[arow][achk]) = pbh0; *(uint4*)(&sBh[arow+32][achk]) = pbh1;
        *(uint4*)(&sBl[arow][achk]) = pbl0; *(uint4*)(&sBl[arow+32][achk]) = pbl1;
        __syncthreads();
        int kn = k0 + 64;
        if (kn < G3_) { LOAD_A(kn); LOAD_B(kn); }
#pragma unroll
        for (int ks = 0; ks < 64; ks += 32) {
            bf16x8 ah = *(const bf16x8*)(&sAh[wm + l15][ks + q*8]);
            bf16x8 al = *(const bf16x8*)(&sAl[wm + l15][ks + q*8]);
            bf16x8 b0h = *(const bf16x8*)(&sBh[wn + l15][ks + q*8]);
            bf16x8 b1h = *(const bf16x8*)(&sBh[wn + 16 + l15][ks + q*8]);
            bf16x8 b0l = *(const bf16x8*)(&sBl[wn + l15][ks + q*8]);
            bf16x8 b1l = *(const bf16x8*)(&sBl[wn + 16 + l15][ks + q*8]);
            acc[0] = MFMA(ah, b0h, acc[0], 0,0,0);
            acc[0] = MFMA(ah, b0l, acc[0], 0,0,0);
            acc[0] = MFMA(al, b0h, acc[0], 0,0,0);
            acc[1] = MFMA(ah, b1h, acc[1], 0,0,0);
            acc[1] = MFMA(ah, b1l, acc[1], 0,0,0);
            acc[1] = MFMA(al, b1h, acc[1], 0,0,0);
        }
        __syncthreads();
    }
    #undef LOAD_A
    #undef LOAD_B
    for (int j = 0; j < 2; ++j)
        for (int r = 0; r < 4; ++r) {
            int row = wm + q*4 + r;
            int gm = m0 + row;
            if (gm < M) {
                int d = n0 + wn + j*16 + l15;
                float v = acc[j][r] + sg0[row]*msB[d] + sg1[row]*maB[d]
                        + sg2[row]*miB[d] + srr[row]*rolew[d];
                unsigned short sh, sl; f2bfs(v, sh, sl);
                msgh[(size_t)gm*D_ + d] = sh;
                msgl[(size_t)gm*D_ + d] = sl;
            }
        }
}

// ---------------------------------------------------------------------------
// GRU MFMA GEMM (split, pipelined): gig[M,6144]. cols<3072: msg@Wih^T+bih;
// else h(gather)@Whh^T+bhh. TM=32, TN=128. Grid (48, 25).
// ---------------------------------------------------------------------------
__global__ __launch_bounds__(256) void k_mfma_gru(
    const unsigned short* __restrict__ msgh, const unsigned short* __restrict__ msgl,
    const unsigned short* __restrict__ hh, const unsigned short* __restrict__ hl,
    const int* __restrict__ list, const int* __restrict__ cnt,
    const unsigned short* __restrict__ Wihh, const unsigned short* __restrict__ Wihl,
    const unsigned short* __restrict__ Whhh, const unsigned short* __restrict__ Whhl,
    const float* __restrict__ bih, const float* __restrict__ bhh,
    float* __restrict__ gig)
{
    int M = *cnt;
    int m0 = blockIdx.y * 32; if (m0 >= M) return;
    int n0 = blockIdx.x * 128;
    bool second = (n0 >= G3_);
    int nloc = second ? (n0 - G3_) : n0;
    const unsigned short* Wh = second ? Whhh : Wihh;
    const unsigned short* Wl = second ? Whhl : Wihl;
    const float* bias = second ? (bhh + nloc) : (bih + nloc);
    __shared__ unsigned short sAh[32][72], sAl[32][72];
    __shared__ unsigned short sBh[128][72], sBl[128][72];
    __shared__ int slist[32];
    int tid = threadIdx.x;
    if (tid < 32) {
        int gm = m0 + tid;
        slist[tid] = (gm < M) ? list[gm] : 0;
    }
    __syncthreads();
    int w = tid >> 6, l = tid & 63;
    int l15 = l & 15, q = l >> 4;
    int wn = w * 32;
    int arow = tid >> 3, achk = (tid & 7) * 8;
    int gmA = m0 + arow;
    const unsigned short* aSrcH = second ? (hh + (size_t)slist[arow] * D_)
                                         : (msgh + (size_t)gmA * D_);
    const unsigned short* aSrcL = second ? (hl + (size_t)slist[arow] * D_)
                                         : (msgl + (size_t)gmA * D_);
    f32x4 acc[2][2] = {};
    uint4 pah = make_uint4(0u,0u,0u,0u), pal = pah;
    uint4 pbh[4], pbl[4];
    if (gmA < M) {
        pah = *(const uint4*)(aSrcH + achk);
        pal = *(const uint4*)(aSrcL + achk);
    }
    for (int i = 0; i < 4; ++i) {
        int r = arow + 32 * i;
        pbh[i] = *(const uint4*)(Wh + (size_t)(nloc + r) * D_ + achk);
        pbl[i] = *(const uint4*)(Wl + (size_t)(nloc + r) * D_ + achk);
    }
    for (int k0 = 0; k0 < D_; k0 += 64) {
        *(uint4*)(&sAh[arow][achk]) = pah;
        *(uint4*)(&sAl[arow][achk]) = pal;
        for (int i = 0; i < 4; ++i) {
            *(uint4*)(&sBh[arow + 32*i][achk]) = pbh[i];
            *(uint4*)(&sBl[arow + 32*i][achk]) = pbl[i];
        }
        __syncthreads();
        int kn = k0 + 64;
        if (kn < D_) {
            if (gmA < M) {
                pah = *(const uint4*)(aSrcH + kn + achk);
                pal = *(const uint4*)(aSrcL + kn + achk);
            }
            for (int i = 0; i < 4; ++i) {
                int r = arow + 32 * i;
                pbh[i] = *(const uint4*)(Wh + (size_t)(nloc + r) * D_ + kn + achk);
                pbl[i] = *(const uint4*)(Wl + (size_t)(nloc + r) * D_ + kn + achk);
            }
        }
#pragma unroll
        for (int ks = 0; ks < 64; ks += 32) {
            bf16x8 a0h = *(const bf16x8*)(&sAh[l15][ks + q*8]);
            bf16x8 a1h = *(const bf16x8*)(&sAh[16 + l15][ks + q*8]);
            bf16x8 a0l = *(const bf16x8*)(&sAl[l15][ks + q*8]);
            bf16x8 a1l = *(const bf16x8*)(&sAl[16 + l15][ks + q*8]);
            bf16x8 b0h = *(const bf16x8*)(&sBh[wn + l15][ks + q*8]);
            bf16x8 b1h = *(const bf16x8*)(&sBh[wn + 16 + l15][ks + q*8]);
            bf16x8 b0l = *(const bf16x8*)(&sBl[wn + l15][ks + q*8]);
            bf16x8 b1l = *(const bf16x8*)(&sBl[wn + 16 + l15][ks + q*8]);
            acc[0][0] = MFMA(a0h, b0h, acc[0][0], 0,0,0);
            acc[0][0] = MFMA(a0h, b0l, acc[0][0], 0,0,0);
            acc[0][0] = MFMA(a0l, b0h, acc[0][0], 0,0,0);
            acc[0][1] = MFMA(a0h, b1h, acc[0][1], 0,0,0);
            acc[0][1] = MFMA(a0h, b1l, acc[0][1], 0,0,0);
            acc[0][1] = MFMA(a0l, b1h, acc[0][1], 0,0,0);
            acc[1][0] = MFMA(a1h, b0h, acc[1][0], 0,0,0);
            acc[1][0] = MFMA(a1h, b0l, acc[1][0], 0,0,0);
            acc[1][0] = MFMA(a1l, b0h, acc[1][0], 0,0,0);
            acc[1][1] = MFMA(a1h, b1h, acc[1][1], 0,0,0);
            acc[1][1] = MFMA(a1h, b1l, acc[1][1], 0,0,0);
            acc[1][1] = MFMA(a1l, b1h, acc[1][1], 0,0,0);
        }
        __syncthreads();
    }
    for (int mi = 0; mi < 2; ++mi)
        for (int nj = 0; nj < 2; ++nj)
            for (int r = 0; r < 4; ++r) {
                int row = mi*16 + q*4 + r;
                int gm = m0 + row;
                if (gm < M) {
                    int cl = wn + nj*16 + l15;
                    gig[(size_t)gm * G6_ + n0 + cl] = acc[mi][nj][r] + bias[cl];
                }
            }
}

// ---------------------------------------------------------------------------
// Step F: GRU gates + LN + clip, masked write into h (+split mirror).
// gig layout: [row][0:3072]=gi, [row][3072:6144]=gh
// ---------------------------------------------------------------------------
__global__ __launch_bounds__(256) void k_gru_fin(
    const float* __restrict__ gig,
    const int* __restrict__ list, const int* __restrict__ cnt,
    const float* __restrict__ ulng, const float* __restrict__ ulnb,
    float* __restrict__ h, unsigned short* __restrict__ hh, unsigned short* __restrict__ hl)
{
    int row = blockIdx.x;
    if (row >= *cnt) return;
    int bn = list[row];
    int tid = threadIdx.x;
    const float* gi = gig + (size_t)row * G6_;
    const float* gh = gi + G3_;
    float u[4]; float lsum = 0.f;
    for (int k = 0; k < 4; ++k) {
        int d = tid + 256*k;
        float ir = gi[d], iz = gi[D_ + d], in_ = gi[2*D_ + d];
        float hr = gh[d], hz = gh[D_ + d], hn = gh[2*D_ + d];
        float hv = h[(size_t)bn*D_ + d];
        float r = 1.f / (1.f + expf(-(ir + hr)));
        float z = 1.f / (1.f + expf(-(iz + hz)));
        float nn = tanhf(in_ + r * hn);
        u[k] = (1.f - z) * nn + z * hv;
        lsum += u[k];
    }
    float mean = block_sum(lsum) * (1.f / D_);
    float lv = 0.f;
    for (int k = 0; k < 4; ++k) { float d = u[k] - mean; lv += d * d; }
    float inv = rsqrtf(block_sum(lv) * (1.f / D_) + 1e-5f);
    for (int k = 0; k < 4; ++k) {
        int d = tid + 256*k;
        float y = (u[k] - mean) * inv * ulng[d] + ulnb[d];
        y = fminf(fmaxf(y, -50.f), 50.f);
        h[(size_t)bn*D_ + d] = y;
        unsigned short sh, sl; f2bfs(y, sh, sl);
        hh[(size_t)bn*D_ + d] = sh;
        hl[(size_t)bn*D_ + d] = sl;
    }
}

// ---------------------------------------------------------------------------
// Final: buf = LN(buf + scene, res_ln) in-place; also split copy to H planes.
// ---------------------------------------------------------------------------
__global__ __launch_bounds__(256) void k_resln(
    float* __restrict__ buf, const float* __restrict__ scene,
    const float* __restrict__ g, const float* __restrict__ bt,
    unsigned short* __restrict__ Hh, unsigned short* __restrict__ Hl)
{
    size_t row = blockIdx.x;
    int tid = threadIdx.x;
    float x[4]; float lsum = 0.f;
    for (int k = 0; k < 4; ++k) {
        int d = tid + 256*k;
        x[k] = buf[row*D_ + d] + scene[row*D_ + d];
        lsum += x[k];
    }
    float mean = block_sum(lsum) * (1.f / D_);
    float lv = 0.f;
    for (int k = 0; k < 4; ++k) { float d = x[k] - mean; lv += d * d; }
    float inv = rsqrtf(block_sum(lv) * (1.f / D_) + 1e-5f);
    for (int k = 0; k < 4; ++k) {
        int d = tid + 256*k;
        float y = (x[k] - mean) * inv * g[d] + bt[d];
        buf[row*D_ + d] = y;
        unsigned short sh, sl; f2bfs(y, sh, sl);
        Hh[row*D_ + d] = sh;
        Hl[row*D_ + d] = sl;
    }
}

// ---------------------------------------------------------------------------
// Final: H = LN(gelu(G), eo_ln); plus h_fin copy blocks.
// ---------------------------------------------------------------------------
__global__ __launch_bounds__(256) void k_final(
    const float* __restrict__ G, const float* __restrict__ g, const float* __restrict__ bt,
    float* __restrict__ outH, const float* __restrict__ h, float* __restrict__ outh)
{
    int tid = threadIdx.x;
    if (blockIdx.x < B_*S_) {
        size_t row = blockIdx.x;
        float x[4]; float lsum = 0.f;
        for (int k = 0; k < 4; ++k) {
            x[k] = gelu_f(G[row*D_ + tid + 256*k]);
            lsum += x[k];
        }
        float mean = block_sum(lsum) * (1.f / D_);
        float lv = 0.f;
        for (int k = 0; k < 4; ++k) { float d = x[k] - mean; lv += d * d; }
        float inv = rsqrtf(block_sum(lv) * (1.f / D_) + 1e-5f);
        for (int k = 0; k < 4; ++k) {
            int d = tid + 256*k;
            outH[row*D_ + d] = (x[k] - mean) * inv * g[d] + bt[d];
        }
    } else {
        size_t bn = blockIdx.x - B_*S_;
        for (int d = tid; d < D_; d += 256)
            outh[bn*D_ + d] = h[bn*D_ + d];
    }
}

// ---------------------------------------------------------------------------
extern "C" void kernel_launch(void* const* d_in, const int* in_sizes, int n_in,
                              void* d_out, int out_size, void* d_ws, size_t ws_size,
                              hipStream_t stream)
{
    const float* scene = (const float*)d_in[0];
    const float* inc   = (const float*)d_in[1];
    const int*   etype = (const int*)d_in[3];
    const int*   emask = (const int*)d_in[4];
    const float* nemb  = (const float*)d_in[5];
    const float* temb  = (const float*)d_in[6];
    const float* nameW = (const float*)d_in[7];
    const float* nlg   = (const float*)d_in[8];
    const float* nlb   = (const float*)d_in[9];
    const float* n2eW  = (const float*)d_in[10];
    const float* n2eb  = (const float*)d_in[11];
    const float* t2eW  = (const float*)d_in[12];
    const float* t2eb  = (const float*)d_in[13];
    const float* elng  = (const float*)d_in[14];
    const float* elnb  = (const float*)d_in[15];
    const float* gW1   = (const float*)d_in[16];
    const float* gb1   = (const float*)d_in[17];
    const float* gW2   = (const float*)d_in[18];
    const float* gb2   = (const float*)d_in[19];
    const float* msW   = (const float*)d_in[20];
    const float* msB   = (const float*)d_in[21];
    const float* maW   = (const float*)d_in[22];
    const float* maB   = (const float*)d_in[23];
    const float* miW   = (const float*)d_in[24];
    const float* miB   = (const float*)d_in[25];
    const float* rolew = (const float*)d_in[26];
    const float* Wih   = (const float*)d_in[27];
    const float* Whh   = (const float*)d_in[28];
    const float* bih   = (const float*)d_in[29];
    const float* bhh   = (const float*)d_in[30];
    const float* ulng  = (const float*)d_in[31];
    const float* ulnb  = (const float*)d_in[32];
    const float* eoW   = (const float*)d_in[33];
    const float* eoB   = (const float*)d_in[34];
    const float* eolng = (const float*)d_in[35];
    const float* eolnb = (const float*)d_in[36];
    const float* rlng  = (const float*)d_in[37];
    const float* rlnb  = (const float*)d_in[38];

    float* outH = (float*)d_out;                    // [B,S,D] — doubles as ebuf
    float* outh = outH + (size_t)B_*S_*D_;          // [B,N,D] h_fin

    float* W = (float*)d_ws;
    size_t o = 0;
    float* roles    = W + o; o += BN_;
    float* mean_ent = W + o; o += (size_t)B_*D_;
    float* e_pre    = W + o; o += (size_t)B_*D_;
    float* gatep    = W + o; o += B_*4;
    float* rowrole  = W + o; o += BN_;
    int*   cnt      = (int*)(W + o); o += 4;
    int*   list     = (int*)(W + o); o += BN_;
    float* ctxa     = W + o; o += (size_t)BN_*D_;
    float* ctxi     = W + o; o += (size_t)BN_*D_;
    float* hbuf     = W + o; o += (size_t)BN_*D_;
    float* gig      = W + o; o += (size_t)BN_*G6_;  // also P (init) and G (final)
    unsigned short* U = (unsigned short*)(W + o);
    size_t uo = 0;
    unsigned short* msgh  = U + uo; uo += (size_t)BN_*D_;
    unsigned short* msgl  = U + uo; uo += (size_t)BN_*D_;
    unsigned short* hh    = U + uo; uo += (size_t)BN_*D_;
    unsigned short* hl    = U + uo; uo += (size_t)BN_*D_;
    unsigned short* Hh    = U + uo; uo += (size_t)B_*S_*D_;
    unsigned short* Hl    = U + uo; uo += (size_t)B_*S_*D_;
    unsigned short* Wcath = U + uo; uo += (size_t)D_*G3_;
    unsigned short* Wcatl = U + uo; uo += (size_t)D_*G3_;
    unsigned short* Wihh  = U + uo; uo += (size_t)G3_*D_;
    unsigned short* Wihl  = U + uo; uo += (size_t)G3_*D_;
    unsigned short* Whhh  = U + uo; uo += (size_t)G3_*D_;
    unsigned short* Whhl  = U + uo; uo += (size_t)G3_*D_;
    unsigned short* eoWh  = U + uo; uo += (size_t)D_*D_;
    unsigned short* eoWl  = U + uo; uo += (size_t)D_*D_;
    unsigned short* nWh   = U + uo; uo += (size_t)D_*ND_;
    unsigned short* nWl   = U + uo; uo += (size_t)D_*ND_;
    unsigned short* nEh   = U + uo; uo += (size_t)BN_*ND_;
    unsigned short* nEl   = U + uo; uo += (size_t)BN_*ND_;

    // ---- weight conversion (per call; inputs restored each timed call) ----
    #define CVT(src, dh, dl, r, c, ld) \
        k_f2bfsplit<<<(((size_t)(r)*(c)/4 + 255)/256), 256, 0, stream>>>(src, dh, dl, r, c, ld)
    CVT(Wih,   Wihh, Wihl,            G3_, D_,  D_);
    CVT(Whh,   Whhh, Whhl,            G3_, D_,  D_);
    CVT(msW,   Wcath + 0,    Wcatl + 0,    D_, D_, G3_);
    CVT(maW,   Wcath + D_,   Wcatl + D_,   D_, D_, G3_);
    CVT(miW,   Wcath + 2*D_, Wcatl + 2*D_, D_, D_, G3_);
    CVT(nameW, nWh, nWl,              D_,  ND_, ND_);
    CVT(nemb,  nEh, nEl,              BN_, ND_, ND_);
    CVT(eoW,   eoWh, eoWl,            D_,  D_,  D_);
    #undef CVT

    // init: P = name_embs @ name_W^T (split MFMA) ; h0 (+ split mirror)
    k_mfma_nt<<<dim3(D_/128, (BN_+31)/32), 256, 0, stream>>>(
        nEh, nEl, nWh, nWl, nullptr, gig, BN_, D_, ND_);
    k_h0<<<BN_, 256, 0, stream>>>(gig, etype, emask, temb, nlg, nlb, hbuf, hh, hl);

    for (int s = 0; s < S_; ++s) {
        k_step_a<<<dim3(B_, 4), 256, 0, stream>>>(inc, emask, hbuf, roles, mean_ent, cnt, s);
        k_step_b<<<NB_EPRE + BN_, 256, 0, stream>>>(scene, inc, hbuf, outH,
            n2eW, n2eb, t2eW, t2eb, roles, mean_ent, e_pre, ctxa, ctxi, cnt, list, rowrole, s);
        k_step_c<<<B_, 256, 0, stream>>>(e_pre, elng, elnb, gW1, gb1, gW2, gb2, outH, gatep, s);
        k_mfma_msg<<<dim3(16, (BN_+31)/32), 256, 0, stream>>>(ctxa, ctxi, outH, Wcath, Wcatl,
            gatep, list, cnt, rowrole, msB, maB, miB, rolew, msgh, msgl, s);
        k_mfma_gru<<<dim3(48, (BN_+31)/32), 256, 0, stream>>>(msgh, msgl, hh, hl, list, cnt,
            Wihh, Wihl, Whhh, Whhl, bih, bhh, gig);
        k_gru_fin<<<BN_, 256, 0, stream>>>(gig, list, cnt, ulng, ulnb, hbuf, hh, hl);
    }

    // epilogue: H = LN(gelu(LN(es + scene) @ eo_W^T + eo_b)); h_fin copy
    k_resln<<<B_*S_, 256, 0, stream>>>(outH, scene, rlng, rlnb, Hh, Hl);
    k_mfma_nt<<<dim3(D_/128, (B_*S_+31)/32), 256, 0, stream>>>(
        Hh, Hl, eoWh, eoWl, eoB, gig, B_*S_, D_, D_);
    k_final<<<B_*S_ + BN_, 256, 0, stream>>>(gig, eolng, eolnb, outH, hbuf, outh);
}